// Round 10
// baseline (181.675 us; speedup 1.0000x reference)
//
#include <hip/hip_runtime.h>

#define SEQ    1024
#define BATCH  512
#define NTAGS  48
#define CPB    16   // chains per block (MFMA N)

typedef float f32x4 __attribute__((ext_vector_type(4)));
typedef short s16x8 __attribute__((ext_vector_type(8)));

// f32 -> bf16 round-to-nearest-even (for static W)
__device__ __forceinline__ unsigned short f2bf(float x) {
  unsigned u = __float_as_uint(x);
  return (unsigned short)((u + 0x7fffu + ((u >> 16) & 1u)) >> 16);
}
// pack two f32 -> bf16x2 u32 by truncation (state path; cheap, bias ~0.2%)
__device__ __forceinline__ unsigned pk2(float lo, float hi) {
  return (__float_as_uint(hi) & 0xffff0000u) | (__float_as_uint(lo) >> 16);
}

// One wave = 16 chains. State d[tau][r] = S[tag=16*tau+4*q+r][chain=n] (f32,
// MFMA D-layout). Per step: pack->bf16, redistribute tag-axis across lane
// quartets (12 ds_bpermute + selects) into the MFMA B-operand, 6 MFMAs
// (3 tag-tiles x K=48), elementwise exp(em) multiply, renorm every 4 steps
// on the chain pivot (tag 0) broadcast via 1 extra bpermute.
template <int DIR, int MASKED>
__device__ __forceinline__ void run_dir(
    const float* __restrict__ em, const int* __restrict__ mask,
    const float* __restrict__ start_t, const float* __restrict__ end_t,
    const float* __restrict__ trans,
    float* __restrict__ vout, float* __restrict__ cout, int b0)
{
  const int l = threadIdx.x, n = l & 15, q = l >> 4;
  const size_t strideT = (size_t)BATCH * NTAGS;
  const float* eb = em + (size_t)(b0 + n) * NTAGS + 4 * q;

  // Static A fragments: DIR==0 -> W^T (A[m][k] = W[k][16t+m]); DIR==1 -> W.
  // A-layout: row m = lane&15, k = 8*(lane>>4) + j (+32 for kappa=1, 0-pad k>=48)
  s16x8 A[3][2];
#pragma unroll
  for (int tau = 0; tau < 3; ++tau)
#pragma unroll
    for (int kap = 0; kap < 2; ++kap) {
      s16x8 tmp;
#pragma unroll
      for (int j = 0; j < 8; ++j) {
        int k = 8 * q + j + 32 * kap;
        float w = 0.f;
        if (k < NTAGS)
          w = __expf(DIR == 0 ? trans[k * NTAGS + 16 * tau + n]
                              : trans[(16 * tau + n) * NTAGS + k]);
        tmp[j] = (short)f2bf(w);
      }
      A[tau][kap] = tmp;
    }

  // init state
  f32x4 d[3];
#pragma unroll
  for (int tau = 0; tau < 3; ++tau) {
    if (DIR == 0) {
      f32x4 s4 = *(const f32x4*)(start_t + 16 * tau + 4 * q);
      f32x4 e4 = *(const f32x4*)(eb + 16 * tau);
#pragma unroll
      for (int r = 0; r < 4; ++r) d[tau][r] = __expf(s4[r] + e4[r]);
    } else {
      f32x4 e4 = *(const f32x4*)(end_t + 16 * tau + 4 * q);
#pragma unroll
      for (int r = 0; r < 4; ++r) d[tau][r] = __expf(e4[r]);
    }
  }

  const int ilo = (n + 32 * (q & 1)) << 2;   // bpermute byte idx, lo 4 tags
  const int ihi = ilo + 64;                  // +16 lanes
  const int ipv = n << 2;                    // pivot: lane n (q=0, tag 0)
  const bool hlo = (l < 32);

  float cX = 0.f;
  f32x4 Exc[3], Lr[3];
  int Mc = 1, Mr = 1;
  {
    const int t0 = (DIR == 0) ? 1 : 1023;
    const int t1 = (DIR == 0) ? 2 : 1022;
#pragma unroll
    for (int tau = 0; tau < 3; ++tau) {
      f32x4 raw = *(const f32x4*)(eb + (size_t)t0 * strideT + 16 * tau);
#pragma unroll
      for (int r = 0; r < 4; ++r) Exc[tau][r] = __expf(raw[r]);
      Lr[tau] = *(const f32x4*)(eb + (size_t)t1 * strideT + 16 * tau);
    }
    if (MASKED) { Mc = mask[t0 * BATCH + b0 + n]; Mr = mask[t1 * BATCH + b0 + n]; }
  }

  auto step = [&](int t, bool rn) {
    int t2 = (DIR == 0) ? ((t + 2 > 511) ? 511 : t + 2)
                        : ((t - 2 < 512) ? 512 : t - 2);
    // source of the exchange: fwd = state (Ex applied post-MFMA);
    // bwd = state*Ex (pre-multiply)
    f32x4 v0, v1, v2;
    if (DIR == 0) { v0 = d[0]; v1 = d[1]; v2 = d[2]; }
    else          { v0 = d[0] * Exc[0]; v1 = d[1] * Exc[1]; v2 = d[2] * Exc[2]; }
    unsigned P00 = pk2(v0[0], v0[1]), P01 = pk2(v0[2], v0[3]);
    unsigned P10 = pk2(v1[0], v1[1]), P11 = pk2(v1[2], v1[3]);
    unsigned P20 = pk2(v2[0], v2[1]), P21 = pk2(v2[2], v2[3]);
    int pvi = 0;
    if (rn) pvi = __builtin_amdgcn_ds_bpermute(ipv, __float_as_int(v0[0]));
    int a00 = __builtin_amdgcn_ds_bpermute(ilo, (int)P00);
    int a01 = __builtin_amdgcn_ds_bpermute(ilo, (int)P01);
    int a02 = __builtin_amdgcn_ds_bpermute(ihi, (int)P00);
    int a03 = __builtin_amdgcn_ds_bpermute(ihi, (int)P01);
    int a10 = __builtin_amdgcn_ds_bpermute(ilo, (int)P10);
    int a11 = __builtin_amdgcn_ds_bpermute(ilo, (int)P11);
    int a12 = __builtin_amdgcn_ds_bpermute(ihi, (int)P10);
    int a13 = __builtin_amdgcn_ds_bpermute(ihi, (int)P11);
    int a20 = __builtin_amdgcn_ds_bpermute(ilo, (int)P20);
    int a21 = __builtin_amdgcn_ds_bpermute(ilo, (int)P21);
    int a22 = __builtin_amdgcn_ds_bpermute(ihi, (int)P20);
    int a23 = __builtin_amdgcn_ds_bpermute(ihi, (int)P21);
    int4 B0i, B1i;
    B0i.x = hlo ? a00 : a10;  B0i.y = hlo ? a01 : a11;
    B0i.z = hlo ? a02 : a12;  B0i.w = hlo ? a03 : a13;
    B1i.x = hlo ? a20 : 0;    B1i.y = hlo ? a21 : 0;
    B1i.z = hlo ? a22 : 0;    B1i.w = hlo ? a23 : 0;
    s16x8 B0 = __builtin_bit_cast(s16x8, B0i);
    s16x8 B1 = __builtin_bit_cast(s16x8, B1i);
    const f32x4 z4 = {0.f, 0.f, 0.f, 0.f};
    f32x4 n0 = __builtin_amdgcn_mfma_f32_16x16x32_bf16(A[0][0], B0, z4, 0, 0, 0);
    f32x4 n1 = __builtin_amdgcn_mfma_f32_16x16x32_bf16(A[1][0], B0, z4, 0, 0, 0);
    f32x4 n2 = __builtin_amdgcn_mfma_f32_16x16x32_bf16(A[2][0], B0, z4, 0, 0, 0);
    n0 = __builtin_amdgcn_mfma_f32_16x16x32_bf16(A[0][1], B1, n0, 0, 0, 0);
    n1 = __builtin_amdgcn_mfma_f32_16x16x32_bf16(A[1][1], B1, n1, 0, 0, 0);
    n2 = __builtin_amdgcn_mfma_f32_16x16x32_bf16(A[2][1], B1, n2, 0, 0, 0);
    if (DIR == 0) { n0 *= Exc[0]; n1 *= Exc[1]; n2 *= Exc[2]; }
    // prefetch em (and mask) for t2
    f32x4 Ln0 = *(const f32x4*)(eb + (size_t)t2 * strideT);
    f32x4 Ln1 = *(const f32x4*)(eb + (size_t)t2 * strideT + 16);
    f32x4 Ln2 = *(const f32x4*)(eb + (size_t)t2 * strideT + 32);
    int Mn = 1;
    if (MASKED) Mn = mask[t2 * BATCH + b0 + n];
    const bool mk = (!MASKED) || (Mc != 0);
    if (rn) {
      float pv = __int_as_float(pvi);
      float rm = __builtin_amdgcn_rcpf(pv);
      cX += __logf(pv);
      d[0] = (mk ? n0 : d[0]) * rm;
      d[1] = (mk ? n1 : d[1]) * rm;
      d[2] = (mk ? n2 : d[2]) * rm;
    } else {
      d[0] = mk ? n0 : d[0];
      d[1] = mk ? n1 : d[1];
      d[2] = mk ? n2 : d[2];
    }
#pragma unroll
    for (int r = 0; r < 4; ++r) {
      Exc[0][r] = __expf(Lr[0][r]);
      Exc[1][r] = __expf(Lr[1][r]);
      Exc[2][r] = __expf(Lr[2][r]);
    }
    Lr[0] = Ln0; Lr[1] = Ln1; Lr[2] = Ln2;
    Mc = Mr; Mr = Mn;
  };

  if (DIR == 0) {
    for (int t = 1; t <= 505; t += 4) {
      step(t, false); step(t + 1, false); step(t + 2, false); step(t + 3, true);
    }
    step(509, false); step(510, false); step(511, false);   // alpha_511
  } else {
    for (int u = 1023; u >= 515; u -= 4) {
      step(u, false); step(u - 1, false); step(u - 2, false); step(u - 3, true);
    }                                                        // beta_512
  }

#pragma unroll
  for (int tau = 0; tau < 3; ++tau)
    *(f32x4*)(vout + (size_t)(b0 + n) * NTAGS + 16 * tau + 4 * q) = d[tau];
  if (l < 16) cout[b0 + l] = cX;
}

__global__ __launch_bounds__(64) void crf_mfma_kernel(
    const float* __restrict__ em, const int* __restrict__ tags,
    const int* __restrict__ mask, const float* __restrict__ start_t,
    const float* __restrict__ end_t, const float* __restrict__ trans,
    float* __restrict__ alpha, float* __restrict__ beta,
    float* __restrict__ cfb, float* __restrict__ cbb,
    float* __restrict__ numb)
{
  const int bid = blockIdx.x;
  const int l = threadIdx.x;
  const size_t strideT = (size_t)BATCH * NTAGS;

  if (bid >= 64) {
    // -------- numerator for chain b (one wave per chain) --------
    const int b = bid - 64;
    float np = 0.f; int mcount = 0;
    for (int t = l; t < SEQ; t += 64) {
      int tag_t = tags[(size_t)t * BATCH + b];
      tag_t = min(max(tag_t, 0), NTAGS - 1);
      int mk = mask[t * BATCH + b];
      float e = em[(size_t)t * strideT + (size_t)b * NTAGS + tag_t];
      if (t == 0) np += start_t[tag_t] + e;
      else {
        int tag_p = tags[(size_t)(t - 1) * BATCH + b];
        tag_p = min(max(tag_p, 0), NTAGS - 1);
        np += (trans[tag_p * NTAGS + tag_t] + e) * (float)mk;
      }
      mcount += (mk != 0) ? 1 : 0;
    }
#pragma unroll
    for (int off = 32; off > 0; off >>= 1) {
      np += __shfl_xor(np, off);
      mcount += __shfl_xor(mcount, off);
    }
    int last_idx = min(max(mcount - 1, 0), SEQ - 1);
    int tag_last = tags[(size_t)last_idx * BATCH + b];
    tag_last = min(max(tag_last, 0), NTAGS - 1);
    if (l == 0) numb[b] = np + end_t[tag_last];
    return;
  }

  const int dir = bid >> 5;           // 0: fwd (blocks 0..31), 1: bwd (32..63)
  const int b0 = (bid & 31) * CPB;

  // all-ones mask check for this 16-chain group
  int myall = 1;
  for (int i = l; i < SEQ * CPB / 4; i += 64) {
    int fi = i << 2;
    int t = fi >> 4, c = fi & 15;
    int4 v = *(const int4*)&mask[t * BATCH + b0 + c];
    myall &= (v.x != 0) & (v.y != 0) & (v.z != 0) & (v.w != 0);
  }
  const bool allones = (__ballot(myall != 0) == ~0ull);

  if (dir == 0) {
    if (allones) run_dir<0, 0>(em, mask, start_t, end_t, trans, alpha, cfb, b0);
    else         run_dir<0, 1>(em, mask, start_t, end_t, trans, alpha, cfb, b0);
  } else {
    if (allones) run_dir<1, 0>(em, mask, start_t, end_t, trans, beta, cbb, b0);
    else         run_dir<1, 1>(em, mask, start_t, end_t, trans, beta, cbb, b0);
  }
}

// den = cf + cb + log(alpha_511 . beta_512); out = mean(num - den)
__global__ __launch_bounds__(512) void crf_combine_kernel(
    const float* __restrict__ alpha, const float* __restrict__ beta,
    const float* __restrict__ cfb,   const float* __restrict__ cbb,
    const float* __restrict__ numb,  float* __restrict__ out)
{
  const int tid = threadIdx.x;       // 0..511 = chain
  float dot = 0.0f;
#pragma unroll
  for (int j = 0; j < NTAGS; j += 4) {
    float4 av = *(const float4*)&alpha[tid * NTAGS + j];
    float4 bv = *(const float4*)&beta [tid * NTAGS + j];
    dot += av.x * bv.x + av.y * bv.y + av.z * bv.z + av.w * bv.w;
  }
  float den = cfb[tid] + cbb[tid] + __logf(dot);
  float v   = numb[tid] - den;
#pragma unroll
  for (int off = 32; off > 0; off >>= 1)
    v += __shfl_xor(v, off);
  __shared__ float sw[8];
  if ((tid & 63) == 0) sw[tid >> 6] = v;
  __syncthreads();
  if (tid == 0) {
    float s = 0.0f;
#pragma unroll
    for (int w = 0; w < 8; ++w) s += sw[w];
    out[0] = s * (1.0f / (float)BATCH);
  }
}

extern "C" void kernel_launch(void* const* d_in, const int* in_sizes, int n_in,
                              void* d_out, int out_size, void* d_ws, size_t ws_size,
                              hipStream_t stream) {
  const float* em   = (const float*)d_in[0];
  const int*   tg   = (const int*)  d_in[1];
  const int*   mask = (const int*)  d_in[2];
  const float* st   = (const float*)d_in[3];
  const float* en   = (const float*)d_in[4];
  const float* tr   = (const float*)d_in[5];

  float* ws    = (float*)d_ws;
  float* alpha = ws;                              // 512*48
  float* beta  = ws + BATCH * NTAGS;              // 512*48
  float* cfb   = ws + 2 * BATCH * NTAGS;          // 512
  float* cbb   = cfb + BATCH;                     // 512
  float* numb  = cbb + BATCH;                     // 512

  crf_mfma_kernel<<<64 + BATCH, 64, 0, stream>>>(em, tg, mask, st, en, tr,
                                                 alpha, beta, cfb, cbb, numb);
  crf_combine_kernel<<<1, 512, 0, stream>>>(alpha, beta, cfb, cbb, numb,
                                            (float*)d_out);
}

// Round 11
// 168.904 us; speedup vs baseline: 1.0756x; 1.0756x over previous
//
#include <hip/hip_runtime.h>

#define SEQ    1024
#define BATCH  512
#define NTAGS  48
#define CPB    16   // chains per block (MFMA N)

typedef float f32x4 __attribute__((ext_vector_type(4)));
typedef short s16x8 __attribute__((ext_vector_type(8)));

__device__ __forceinline__ unsigned short f2bf(float x) {
  unsigned u = __float_as_uint(x);
  return (unsigned short)((u + 0x7fffu + ((u >> 16) & 1u)) >> 16);
}
__device__ __forceinline__ unsigned pk2(float lo, float hi) {
  return (__float_as_uint(hi) & 0xffff0000u) | (__float_as_uint(lo) >> 16);
}

// One wave = 16 chains, MFMA step identical to r10. NEW: emissions staged in
// 4-step register chunks (EA/EB, compile-time indices), loaded one full chunk
// (~1000cy) before consumption so vmcnt(0) never lands on the serial path
// (r10's 2-step rolling prefetch re-created the r3 same-iteration-consume bug).
template <int DIR, int MASKED>
__device__ __forceinline__ void run_dir(
    const float* __restrict__ em, const int* __restrict__ mask,
    const float* __restrict__ start_t, const float* __restrict__ end_t,
    const float* __restrict__ trans,
    float* __restrict__ vout, float* __restrict__ cout, int b0)
{
  const int l = threadIdx.x, n = l & 15, q = l >> 4;
  const size_t strideT = (size_t)BATCH * NTAGS;
  const float* eb = em + (size_t)(b0 + n) * NTAGS + 4 * q;

  // Static A fragments: DIR==0 -> W^T; DIR==1 -> W. (verified r10)
  s16x8 A[3][2];
#pragma unroll
  for (int tau = 0; tau < 3; ++tau)
#pragma unroll
    for (int kap = 0; kap < 2; ++kap) {
      s16x8 tmp;
#pragma unroll
      for (int j = 0; j < 8; ++j) {
        int k = 8 * q + j + 32 * kap;
        float w = 0.f;
        if (k < NTAGS)
          w = __expf(DIR == 0 ? trans[k * NTAGS + 16 * tau + n]
                              : trans[(16 * tau + n) * NTAGS + k]);
        tmp[j] = (short)f2bf(w);
      }
      A[tau][kap] = tmp;
    }

  // init state
  f32x4 d[3];
#pragma unroll
  for (int tau = 0; tau < 3; ++tau) {
    if (DIR == 0) {
      f32x4 s4 = *(const f32x4*)(start_t + 16 * tau + 4 * q);
      f32x4 e4 = *(const f32x4*)(eb + 16 * tau);
#pragma unroll
      for (int r = 0; r < 4; ++r) d[tau][r] = __expf(s4[r] + e4[r]);
    } else {
      f32x4 e4 = *(const f32x4*)(end_t + 16 * tau + 4 * q);
#pragma unroll
      for (int r = 0; r < 4; ++r) d[tau][r] = __expf(e4[r]);
    }
  }

  const int ilo = (n + 32 * (q & 1)) << 2;
  const int ihi = ilo + 64;
  const int ipv = n << 2;
  const bool hlo = (l < 32);
  float cX = 0.f;
  f32x4 Exc[3];

  // step time: fwd t = 4k+p (chunk0 runs p=1..3); bwd u = 1023-4k-p
#define TIDX(k, p) ((DIR == 0) ? (4 * (k) + (p)) : (1023 - 4 * (k) - (p)))

  f32x4 EA[12], EB[12];   // [p*3 + tau], p = 0..3
  int   MA[4], MB[4];

#define LOADE(BUF, MBUF, k) do {                                      \
    _Pragma("unroll")                                                 \
    for (int p_ = 0; p_ < 4; ++p_) {                                  \
      size_t off_ = (size_t)TIDX(k, p_) * strideT;                    \
      BUF[p_ * 3 + 0] = *(const f32x4*)(eb + off_);                   \
      BUF[p_ * 3 + 1] = *(const f32x4*)(eb + off_ + 16);              \
      BUF[p_ * 3 + 2] = *(const f32x4*)(eb + off_ + 32);              \
      if (MASKED) MBUF[p_] = mask[TIDX(k, p_) * BATCH + b0 + n];      \
    }                                                                 \
  } while (0)

#define VEXP4(D, S) do {                                              \
    _Pragma("unroll")                                                 \
    for (int r_ = 0; r_ < 4; ++r_) (D)[r_] = __expf((S)[r_]);         \
  } while (0)

  // One step at compile-time chunk position p. CUR/NXT: current/next chunk
  // register buffers. MC: this step's mask value (1 if !MASKED).
#define STEPM(p, CUR, NXT, MC) do {                                   \
    f32x4 v0, v1, v2;                                                 \
    if (DIR == 0) { v0 = d[0]; v1 = d[1]; v2 = d[2]; }                \
    else { v0 = d[0] * Exc[0]; v1 = d[1] * Exc[1]; v2 = d[2] * Exc[2]; } \
    unsigned P00 = pk2(v0[0], v0[1]), P01 = pk2(v0[2], v0[3]);        \
    unsigned P10 = pk2(v1[0], v1[1]), P11 = pk2(v1[2], v1[3]);        \
    unsigned P20 = pk2(v2[0], v2[1]), P21 = pk2(v2[2], v2[3]);        \
    int pvi = 0;                                                      \
    if ((p) == 3) pvi = __builtin_amdgcn_ds_bpermute(ipv, __float_as_int(v0[0])); \
    int a00 = __builtin_amdgcn_ds_bpermute(ilo, (int)P00);            \
    int a01 = __builtin_amdgcn_ds_bpermute(ilo, (int)P01);            \
    int a02 = __builtin_amdgcn_ds_bpermute(ihi, (int)P00);            \
    int a03 = __builtin_amdgcn_ds_bpermute(ihi, (int)P01);            \
    int a10 = __builtin_amdgcn_ds_bpermute(ilo, (int)P10);            \
    int a11 = __builtin_amdgcn_ds_bpermute(ilo, (int)P11);            \
    int a12 = __builtin_amdgcn_ds_bpermute(ihi, (int)P10);            \
    int a13 = __builtin_amdgcn_ds_bpermute(ihi, (int)P11);            \
    int a20 = __builtin_amdgcn_ds_bpermute(ilo, (int)P20);            \
    int a21 = __builtin_amdgcn_ds_bpermute(ilo, (int)P21);            \
    int a22 = __builtin_amdgcn_ds_bpermute(ihi, (int)P20);            \
    int a23 = __builtin_amdgcn_ds_bpermute(ihi, (int)P21);            \
    int4 B0i, B1i;                                                    \
    B0i.x = hlo ? a00 : a10;  B0i.y = hlo ? a01 : a11;                \
    B0i.z = hlo ? a02 : a12;  B0i.w = hlo ? a03 : a13;                \
    B1i.x = hlo ? a20 : 0;    B1i.y = hlo ? a21 : 0;                  \
    B1i.z = hlo ? a22 : 0;    B1i.w = hlo ? a23 : 0;                  \
    s16x8 B0 = __builtin_bit_cast(s16x8, B0i);                        \
    s16x8 B1 = __builtin_bit_cast(s16x8, B1i);                        \
    const f32x4 z4 = {0.f, 0.f, 0.f, 0.f};                            \
    f32x4 n0 = __builtin_amdgcn_mfma_f32_16x16x32_bf16(A[0][0], B0, z4, 0, 0, 0); \
    f32x4 n1 = __builtin_amdgcn_mfma_f32_16x16x32_bf16(A[1][0], B0, z4, 0, 0, 0); \
    f32x4 n2 = __builtin_amdgcn_mfma_f32_16x16x32_bf16(A[2][0], B0, z4, 0, 0, 0); \
    n0 = __builtin_amdgcn_mfma_f32_16x16x32_bf16(A[0][1], B1, n0, 0, 0, 0); \
    n1 = __builtin_amdgcn_mfma_f32_16x16x32_bf16(A[1][1], B1, n1, 0, 0, 0); \
    n2 = __builtin_amdgcn_mfma_f32_16x16x32_bf16(A[2][1], B1, n2, 0, 0, 0); \
    if (DIR == 0) { n0 *= Exc[0]; n1 *= Exc[1]; n2 *= Exc[2]; }       \
    const bool mk = (!MASKED) || ((MC) != 0);                         \
    if ((p) == 3) {                                                   \
      float pv = __int_as_float(pvi);                                 \
      float rm = __builtin_amdgcn_rcpf(pv);                           \
      cX += __logf(pv);                                               \
      d[0] = (mk ? n0 : d[0]) * rm;                                   \
      d[1] = (mk ? n1 : d[1]) * rm;                                   \
      d[2] = (mk ? n2 : d[2]) * rm;                                   \
    } else {                                                          \
      d[0] = mk ? n0 : d[0];                                          \
      d[1] = mk ? n1 : d[1];                                          \
      d[2] = mk ? n2 : d[2];                                          \
    }                                                                 \
    /* next step's Exc from resident raw registers */                 \
    if ((p) < 3) {                                                    \
      VEXP4(Exc[0], CUR[((p) + 1) * 3 + 0]);                          \
      VEXP4(Exc[1], CUR[((p) + 1) * 3 + 1]);                          \
      VEXP4(Exc[2], CUR[((p) + 1) * 3 + 2]);                          \
    } else {                                                          \
      VEXP4(Exc[0], NXT[0]);                                          \
      VEXP4(Exc[1], NXT[1]);                                          \
      VEXP4(Exc[2], NXT[2]);                                          \
    }                                                                 \
  } while (0)

#define CHUNKM(CUR, MCUR, NXT, MNXT, k, PSTART) do {                  \
    LOADE(NXT, MNXT, (k) + 1);                                        \
    _Pragma("unroll")                                                 \
    for (int p_ = (PSTART); p_ < 4; ++p_)                             \
      STEPM(p_, CUR, NXT, (MASKED ? MCUR[p_] : 1));                   \
  } while (0)

  LOADE(EA, MA, 0);
  {
    const int pst = (DIR == 0) ? 1 : 0;
    VEXP4(Exc[0], EA[pst * 3 + 0]);
    VEXP4(Exc[1], EA[pst * 3 + 1]);
    VEXP4(Exc[2], EA[pst * 3 + 2]);
  }

  if (DIR == 0) CHUNKM(EA, MA, EB, MB, 0, 1);   // t = 1..3
  else          CHUNKM(EA, MA, EB, MB, 0, 0);   // u = 1023..1020
  for (int k = 1; k <= 125; k += 2) {
    CHUNKM(EB, MB, EA, MA, k,     0);
    CHUNKM(EA, MA, EB, MB, k + 1, 0);
  }
  CHUNKM(EB, MB, EA, MA, 127, 0);               // loads chunk 128 (harmless)

#pragma unroll
  for (int tau = 0; tau < 3; ++tau)
    *(f32x4*)(vout + (size_t)(b0 + n) * NTAGS + 16 * tau + 4 * q) = d[tau];
  if (l < 16) cout[b0 + l] = cX;
}

__global__ __launch_bounds__(64) void crf_mfma_kernel(
    const float* __restrict__ em, const int* __restrict__ tags,
    const int* __restrict__ mask, const float* __restrict__ start_t,
    const float* __restrict__ end_t, const float* __restrict__ trans,
    float* __restrict__ alpha, float* __restrict__ beta,
    float* __restrict__ cfb, float* __restrict__ cbb,
    float* __restrict__ numb)
{
  const int bid = blockIdx.x;
  const int l = threadIdx.x;
  const size_t strideT = (size_t)BATCH * NTAGS;

  if (bid >= 64) {
    // -------- numerator for chain b (one wave per chain) --------
    const int b = bid - 64;
    float np = 0.f; int mcount = 0;
    for (int t = l; t < SEQ; t += 64) {
      int tag_t = tags[(size_t)t * BATCH + b];
      tag_t = min(max(tag_t, 0), NTAGS - 1);
      int mk = mask[t * BATCH + b];
      float e = em[(size_t)t * strideT + (size_t)b * NTAGS + tag_t];
      if (t == 0) np += start_t[tag_t] + e;
      else {
        int tag_p = tags[(size_t)(t - 1) * BATCH + b];
        tag_p = min(max(tag_p, 0), NTAGS - 1);
        np += (trans[tag_p * NTAGS + tag_t] + e) * (float)mk;
      }
      mcount += (mk != 0) ? 1 : 0;
    }
#pragma unroll
    for (int off = 32; off > 0; off >>= 1) {
      np += __shfl_xor(np, off);
      mcount += __shfl_xor(mcount, off);
    }
    int last_idx = min(max(mcount - 1, 0), SEQ - 1);
    int tag_last = tags[(size_t)last_idx * BATCH + b];
    tag_last = min(max(tag_last, 0), NTAGS - 1);
    if (l == 0) numb[b] = np + end_t[tag_last];
    return;
  }

  const int dir = bid >> 5;           // 0: fwd (blocks 0..31), 1: bwd (32..63)
  const int b0 = (bid & 31) * CPB;

  // all-ones mask check for this 16-chain group
  int myall = 1;
  for (int i = l; i < SEQ * CPB / 4; i += 64) {
    int fi = i << 2;
    int t = fi >> 4, c = fi & 15;
    int4 v = *(const int4*)&mask[t * BATCH + b0 + c];
    myall &= (v.x != 0) & (v.y != 0) & (v.z != 0) & (v.w != 0);
  }
  const bool allones = (__ballot(myall != 0) == ~0ull);

  if (dir == 0) {
    if (allones) run_dir<0, 0>(em, mask, start_t, end_t, trans, alpha, cfb, b0);
    else         run_dir<0, 1>(em, mask, start_t, end_t, trans, alpha, cfb, b0);
  } else {
    if (allones) run_dir<1, 0>(em, mask, start_t, end_t, trans, beta, cbb, b0);
    else         run_dir<1, 1>(em, mask, start_t, end_t, trans, beta, cbb, b0);
  }
}

// den = cf + cb + log(alpha_511 . beta_512); out = mean(num - den)
__global__ __launch_bounds__(512) void crf_combine_kernel(
    const float* __restrict__ alpha, const float* __restrict__ beta,
    const float* __restrict__ cfb,   const float* __restrict__ cbb,
    const float* __restrict__ numb,  float* __restrict__ out)
{
  const int tid = threadIdx.x;       // 0..511 = chain
  float dot = 0.0f;
#pragma unroll
  for (int j = 0; j < NTAGS; j += 4) {
    float4 av = *(const float4*)&alpha[tid * NTAGS + j];
    float4 bv = *(const float4*)&beta [tid * NTAGS + j];
    dot += av.x * bv.x + av.y * bv.y + av.z * bv.z + av.w * bv.w;
  }
  float den = cfb[tid] + cbb[tid] + __logf(dot);
  float v   = numb[tid] - den;
#pragma unroll
  for (int off = 32; off > 0; off >>= 1)
    v += __shfl_xor(v, off);
  __shared__ float sw[8];
  if ((tid & 63) == 0) sw[tid >> 6] = v;
  __syncthreads();
  if (tid == 0) {
    float s = 0.0f;
#pragma unroll
    for (int w = 0; w < 8; ++w) s += sw[w];
    out[0] = s * (1.0f / (float)BATCH);
  }
}

extern "C" void kernel_launch(void* const* d_in, const int* in_sizes, int n_in,
                              void* d_out, int out_size, void* d_ws, size_t ws_size,
                              hipStream_t stream) {
  const float* em   = (const float*)d_in[0];
  const int*   tg   = (const int*)  d_in[1];
  const int*   mask = (const int*)  d_in[2];
  const float* st   = (const float*)d_in[3];
  const float* en   = (const float*)d_in[4];
  const float* tr   = (const float*)d_in[5];

  float* ws    = (float*)d_ws;
  float* alpha = ws;                              // 512*48
  float* beta  = ws + BATCH * NTAGS;              // 512*48
  float* cfb   = ws + 2 * BATCH * NTAGS;          // 512
  float* cbb   = cfb + BATCH;                     // 512
  float* numb  = cbb + BATCH;                     // 512

  crf_mfma_kernel<<<64 + BATCH, 64, 0, stream>>>(em, tg, mask, st, en, tr,
                                                 alpha, beta, cfb, cbb, numb);
  crf_combine_kernel<<<1, 512, 0, stream>>>(alpha, beta, cfb, cbb, numb,
                                            (float*)d_out);
}

// Round 12
// 134.846 us; speedup vs baseline: 1.3473x; 1.2526x over previous
//
#include <hip/hip_runtime.h>

#define SEQ    1024
#define BATCH  512
#define NTAGS  48
#define CPB    16   // chains per block (MFMA N)

typedef float f32x4 __attribute__((ext_vector_type(4)));
typedef short s16x8 __attribute__((ext_vector_type(8)));

__device__ __forceinline__ unsigned short f2bf(float x) {
  unsigned u = __float_as_uint(x);
  return (unsigned short)((u + 0x7fffu + ((u >> 16) & 1u)) >> 16);
}
__device__ __forceinline__ unsigned cvtpk(float lo, float hi) {
  unsigned r;
  asm("v_cvt_pk_bf16_f32 %0, %1, %2" : "=v"(r) : "v"(lo), "v"(hi));
  return r;
}
// in-place lane-half swaps (gfx950): after PL32 then PL16 on (X, Y):
//   X = [X_q0, X_q2, Y_q0, Y_q2], Y = [X_q1, X_q3, Y_q1, Y_q3]
#define PL32(a, b) asm("v_permlane32_swap_b32 %0, %1" : "+v"(a), "+v"(b))
#define PL16(a, b) asm("v_permlane16_swap_b32 %0, %1" : "+v"(a), "+v"(b))

// One wave = 16 chains; MFMA data path as verified in r10, but the tag-axis
// redistribution (D-layout -> B-operand) is done entirely with
// v_permlane{32,16}_swap_b32 pairs (VALU, ~4cy) instead of 12 ds_bpermute
// (LDS pipe, ~150cy + lgkmcnt). Derivation: B0even/B0odd per lane-quartet are
// exactly the 2-swap images of (P0[h], P1[h]); B1 from (P2[h], P2[h]).
// Packing via v_cvt_pk_bf16_f32 (1 inst, RNE). Renorm pivot broadcast via the
// same 2-swap chain. Emissions staged in 4-step register chunks (r11).
template <int DIR, int MASKED>
__device__ __forceinline__ void run_dir(
    const float* __restrict__ em, const int* __restrict__ mask,
    const float* __restrict__ start_t, const float* __restrict__ end_t,
    const float* __restrict__ trans,
    float* __restrict__ vout, float* __restrict__ cout, int b0)
{
  const int l = threadIdx.x, n = l & 15, q = l >> 4;
  const size_t strideT = (size_t)BATCH * NTAGS;
  const float* eb = em + (size_t)(b0 + n) * NTAGS + 4 * q;

  // Static A fragments: DIR==0 -> W^T; DIR==1 -> W. (verified r10)
  s16x8 A[3][2];
#pragma unroll
  for (int tau = 0; tau < 3; ++tau)
#pragma unroll
    for (int kap = 0; kap < 2; ++kap) {
      s16x8 tmp;
#pragma unroll
      for (int j = 0; j < 8; ++j) {
        int k = 8 * q + j + 32 * kap;
        float w = 0.f;
        if (k < NTAGS)
          w = __expf(DIR == 0 ? trans[k * NTAGS + 16 * tau + n]
                              : trans[(16 * tau + n) * NTAGS + k]);
        tmp[j] = (short)f2bf(w);
      }
      A[tau][kap] = tmp;
    }

  // init state
  f32x4 d[3];
#pragma unroll
  for (int tau = 0; tau < 3; ++tau) {
    if (DIR == 0) {
      f32x4 s4 = *(const f32x4*)(start_t + 16 * tau + 4 * q);
      f32x4 e4 = *(const f32x4*)(eb + 16 * tau);
#pragma unroll
      for (int r = 0; r < 4; ++r) d[tau][r] = __expf(s4[r] + e4[r]);
    } else {
      f32x4 e4 = *(const f32x4*)(end_t + 16 * tau + 4 * q);
#pragma unroll
      for (int r = 0; r < 4; ++r) d[tau][r] = __expf(e4[r]);
    }
  }

  float cX = 0.f;
  f32x4 Exc[3];

  // step time: fwd t = 4k+p (chunk0 runs p=1..3); bwd u = 1023-4k-p
#define TIDX(k, p) ((DIR == 0) ? (4 * (k) + (p)) : (1023 - 4 * (k) - (p)))

  f32x4 EA[12], EB[12];   // [p*3 + tau], p = 0..3
  int   MA[4], MB[4];

#define LOADE(BUF, MBUF, k) do {                                      \
    _Pragma("unroll")                                                 \
    for (int p_ = 0; p_ < 4; ++p_) {                                  \
      size_t off_ = (size_t)TIDX(k, p_) * strideT;                    \
      BUF[p_ * 3 + 0] = *(const f32x4*)(eb + off_);                   \
      BUF[p_ * 3 + 1] = *(const f32x4*)(eb + off_ + 16);              \
      BUF[p_ * 3 + 2] = *(const f32x4*)(eb + off_ + 32);              \
      if (MASKED) MBUF[p_] = mask[TIDX(k, p_) * BATCH + b0 + n];      \
    }                                                                 \
  } while (0)

#define VEXP4(D, S) do {                                              \
    _Pragma("unroll")                                                 \
    for (int r_ = 0; r_ < 4; ++r_) (D)[r_] = __expf((S)[r_]);         \
  } while (0)

#define STEPM(p, CUR, NXT, MC) do {                                   \
    f32x4 v0, v1, v2;                                                 \
    if (DIR == 0) { v0 = d[0]; v1 = d[1]; v2 = d[2]; }                \
    else { v0 = d[0] * Exc[0]; v1 = d[1] * Exc[1]; v2 = d[2] * Exc[2]; } \
    /* pivot broadcast (renorm steps): q0's v0[0] -> all lanes */     \
    float pv = 0.f;                                                   \
    if ((p) == 3) {                                                   \
      int t1 = __float_as_int(v0[0]), t2 = t1;                        \
      PL32(t1, t2);                                                   \
      int t3 = t1;                                                    \
      PL16(t1, t3);                                                   \
      pv = __int_as_float(t1);                                        \
    }                                                                 \
    /* pack state to bf16x2 dwords P[tau][h] */                       \
    int rx0 = (int)cvtpk(v0[0], v0[1]), rx1 = (int)cvtpk(v0[2], v0[3]); \
    int ry0 = (int)cvtpk(v1[0], v1[1]), ry1 = (int)cvtpk(v1[2], v1[3]); \
    int za0 = (int)cvtpk(v2[0], v2[1]), za1 = (int)cvtpk(v2[2], v2[3]); \
    int zb0 = za0, zb1 = za1;                                         \
    /* 2-swap exchange -> B fragments (matches r10's verified bperm) */ \
    PL32(rx0, ry0); PL16(rx0, ry0);                                   \
    PL32(rx1, ry1); PL16(rx1, ry1);                                   \
    PL32(za0, zb0); PL16(za0, zb0);                                   \
    PL32(za1, zb1); PL16(za1, zb1);                                   \
    int4 B0i = {rx0, rx1, ry0, ry1};                                  \
    int4 B1i = {za0, za1, zb0, zb1};                                  \
    s16x8 B0 = __builtin_bit_cast(s16x8, B0i);                        \
    s16x8 B1 = __builtin_bit_cast(s16x8, B1i);                        \
    const f32x4 z4 = {0.f, 0.f, 0.f, 0.f};                            \
    f32x4 n0 = __builtin_amdgcn_mfma_f32_16x16x32_bf16(A[0][0], B0, z4, 0, 0, 0); \
    f32x4 n1 = __builtin_amdgcn_mfma_f32_16x16x32_bf16(A[1][0], B0, z4, 0, 0, 0); \
    f32x4 n2 = __builtin_amdgcn_mfma_f32_16x16x32_bf16(A[2][0], B0, z4, 0, 0, 0); \
    n0 = __builtin_amdgcn_mfma_f32_16x16x32_bf16(A[0][1], B1, n0, 0, 0, 0); \
    n1 = __builtin_amdgcn_mfma_f32_16x16x32_bf16(A[1][1], B1, n1, 0, 0, 0); \
    n2 = __builtin_amdgcn_mfma_f32_16x16x32_bf16(A[2][1], B1, n2, 0, 0, 0); \
    if (DIR == 0) { n0 *= Exc[0]; n1 *= Exc[1]; n2 *= Exc[2]; }       \
    const bool mk = (!MASKED) || ((MC) != 0);                         \
    if ((p) == 3) {                                                   \
      float rm = __builtin_amdgcn_rcpf(pv);                           \
      cX += __logf(pv);                                               \
      d[0] = (mk ? n0 : d[0]) * rm;                                   \
      d[1] = (mk ? n1 : d[1]) * rm;                                   \
      d[2] = (mk ? n2 : d[2]) * rm;                                   \
    } else {                                                          \
      d[0] = mk ? n0 : d[0];                                          \
      d[1] = mk ? n1 : d[1];                                          \
      d[2] = mk ? n2 : d[2];                                          \
    }                                                                 \
    /* next step's Exc from resident chunk registers */               \
    if ((p) < 3) {                                                    \
      VEXP4(Exc[0], CUR[((p) + 1) * 3 + 0]);                          \
      VEXP4(Exc[1], CUR[((p) + 1) * 3 + 1]);                          \
      VEXP4(Exc[2], CUR[((p) + 1) * 3 + 2]);                          \
    } else {                                                          \
      VEXP4(Exc[0], NXT[0]);                                          \
      VEXP4(Exc[1], NXT[1]);                                          \
      VEXP4(Exc[2], NXT[2]);                                          \
    }                                                                 \
  } while (0)

#define CHUNKM(CUR, MCUR, NXT, MNXT, k, PSTART) do {                  \
    LOADE(NXT, MNXT, (k) + 1);                                        \
    _Pragma("unroll")                                                 \
    for (int p_ = (PSTART); p_ < 4; ++p_)                             \
      STEPM(p_, CUR, NXT, (MASKED ? MCUR[p_] : 1));                   \
  } while (0)

  LOADE(EA, MA, 0);
  {
    const int pst = (DIR == 0) ? 1 : 0;
    VEXP4(Exc[0], EA[pst * 3 + 0]);
    VEXP4(Exc[1], EA[pst * 3 + 1]);
    VEXP4(Exc[2], EA[pst * 3 + 2]);
  }

  if (DIR == 0) CHUNKM(EA, MA, EB, MB, 0, 1);   // t = 1..3
  else          CHUNKM(EA, MA, EB, MB, 0, 0);   // u = 1023..1020
  for (int k = 1; k <= 125; k += 2) {
    CHUNKM(EB, MB, EA, MA, k,     0);
    CHUNKM(EA, MA, EB, MB, k + 1, 0);
  }
  CHUNKM(EB, MB, EA, MA, 127, 0);               // loads chunk 128 (harmless)

#pragma unroll
  for (int tau = 0; tau < 3; ++tau)
    *(f32x4*)(vout + (size_t)(b0 + n) * NTAGS + 16 * tau + 4 * q) = d[tau];
  if (l < 16) cout[b0 + l] = cX;
}

__global__ __launch_bounds__(64) void crf_mfma_kernel(
    const float* __restrict__ em, const int* __restrict__ tags,
    const int* __restrict__ mask, const float* __restrict__ start_t,
    const float* __restrict__ end_t, const float* __restrict__ trans,
    float* __restrict__ alpha, float* __restrict__ beta,
    float* __restrict__ cfb, float* __restrict__ cbb,
    float* __restrict__ numb)
{
  const int bid = blockIdx.x;
  const int l = threadIdx.x;
  const size_t strideT = (size_t)BATCH * NTAGS;

  if (bid >= 64) {
    // -------- numerator for chain b (one wave per chain) --------
    const int b = bid - 64;
    float np = 0.f; int mcount = 0;
    for (int t = l; t < SEQ; t += 64) {
      int tag_t = tags[(size_t)t * BATCH + b];
      tag_t = min(max(tag_t, 0), NTAGS - 1);
      int mk = mask[t * BATCH + b];
      float e = em[(size_t)t * strideT + (size_t)b * NTAGS + tag_t];
      if (t == 0) np += start_t[tag_t] + e;
      else {
        int tag_p = tags[(size_t)(t - 1) * BATCH + b];
        tag_p = min(max(tag_p, 0), NTAGS - 1);
        np += (trans[tag_p * NTAGS + tag_t] + e) * (float)mk;
      }
      mcount += (mk != 0) ? 1 : 0;
    }
#pragma unroll
    for (int off = 32; off > 0; off >>= 1) {
      np += __shfl_xor(np, off);
      mcount += __shfl_xor(mcount, off);
    }
    int last_idx = min(max(mcount - 1, 0), SEQ - 1);
    int tag_last = tags[(size_t)last_idx * BATCH + b];
    tag_last = min(max(tag_last, 0), NTAGS - 1);
    if (l == 0) numb[b] = np + end_t[tag_last];
    return;
  }

  const int dir = bid >> 5;           // 0: fwd (blocks 0..31), 1: bwd (32..63)
  const int b0 = (bid & 31) * CPB;

  // all-ones mask check for this 16-chain group
  int myall = 1;
  for (int i = l; i < SEQ * CPB / 4; i += 64) {
    int fi = i << 2;
    int t = fi >> 4, c = fi & 15;
    int4 v = *(const int4*)&mask[t * BATCH + b0 + c];
    myall &= (v.x != 0) & (v.y != 0) & (v.z != 0) & (v.w != 0);
  }
  const bool allones = (__ballot(myall != 0) == ~0ull);

  if (dir == 0) {
    if (allones) run_dir<0, 0>(em, mask, start_t, end_t, trans, alpha, cfb, b0);
    else         run_dir<0, 1>(em, mask, start_t, end_t, trans, alpha, cfb, b0);
  } else {
    if (allones) run_dir<1, 0>(em, mask, start_t, end_t, trans, beta, cbb, b0);
    else         run_dir<1, 1>(em, mask, start_t, end_t, trans, beta, cbb, b0);
  }
}

// den = cf + cb + log(alpha_511 . beta_512); out = mean(num - den)
__global__ __launch_bounds__(512) void crf_combine_kernel(
    const float* __restrict__ alpha, const float* __restrict__ beta,
    const float* __restrict__ cfb,   const float* __restrict__ cbb,
    const float* __restrict__ numb,  float* __restrict__ out)
{
  const int tid = threadIdx.x;       // 0..511 = chain
  float dot = 0.0f;
#pragma unroll
  for (int j = 0; j < NTAGS; j += 4) {
    float4 av = *(const float4*)&alpha[tid * NTAGS + j];
    float4 bv = *(const float4*)&beta [tid * NTAGS + j];
    dot += av.x * bv.x + av.y * bv.y + av.z * bv.z + av.w * bv.w;
  }
  float den = cfb[tid] + cbb[tid] + __logf(dot);
  float v   = numb[tid] - den;
#pragma unroll
  for (int off = 32; off > 0; off >>= 1)
    v += __shfl_xor(v, off);
  __shared__ float sw[8];
  if ((tid & 63) == 0) sw[tid >> 6] = v;
  __syncthreads();
  if (tid == 0) {
    float s = 0.0f;
#pragma unroll
    for (int w = 0; w < 8; ++w) s += sw[w];
    out[0] = s * (1.0f / (float)BATCH);
  }
}

extern "C" void kernel_launch(void* const* d_in, const int* in_sizes, int n_in,
                              void* d_out, int out_size, void* d_ws, size_t ws_size,
                              hipStream_t stream) {
  const float* em   = (const float*)d_in[0];
  const int*   tg   = (const int*)  d_in[1];
  const int*   mask = (const int*)  d_in[2];
  const float* st   = (const float*)d_in[3];
  const float* en   = (const float*)d_in[4];
  const float* tr   = (const float*)d_in[5];

  float* ws    = (float*)d_ws;
  float* alpha = ws;                              // 512*48
  float* beta  = ws + BATCH * NTAGS;              // 512*48
  float* cfb   = ws + 2 * BATCH * NTAGS;          // 512
  float* cbb   = cfb + BATCH;                     // 512
  float* numb  = cbb + BATCH;                     // 512

  crf_mfma_kernel<<<64 + BATCH, 64, 0, stream>>>(em, tg, mask, st, en, tr,
                                                 alpha, beta, cfb, cbb, numb);
  crf_combine_kernel<<<1, 512, 0, stream>>>(alpha, beta, cfb, cbb, numb,
                                            (float*)d_out);
}